// Round 4
// baseline (71.737 us; speedup 1.0000x reference)
//
#include <hip/hip_runtime.h>
#include <hip/hip_cooperative_groups.h>

// Problem constants (from reference setup_inputs): B=16, N=4096, n_u=n_v=64.
#define BB 16
#define NN 4096
#define NPTS (BB * NN)      // 65536 points
#define NCODE 4096          // 64*64 codes per batch
#define WEIGHT 0.1f

#define NBLK 256            // 1 block/CU -- trivially co-resident for coop launch
#define NTHR 1024           // 4096 waves total -> 16 points per wave

// Single cooperative kernel.
// Phase 0: zero 256KB hist + ctrl. grid.sync.
// Phase 1: argmax codes (16-lane groups, float4 loads, 4 pts/wave/iter) ->
//          device-atomic hist increment.  grid.sync.
// Phase 2: blocks 0..15 scan their batch's 4096 bins, Sum c*(c-1); combine
//          via fenced done-counter (proven in R3); last writes the scalar.
__global__ __launch_bounds__(NTHR, 1) void uniq_fused_kernel(
    const float* __restrict__ u_logits,
    const float* __restrict__ v_logits,
    const int* __restrict__ mask,
    unsigned int* __restrict__ hist,
    unsigned long long* __restrict__ ctrl,
    float* __restrict__ out)
{
    cooperative_groups::grid_group grid = cooperative_groups::this_grid();
    const int t    = threadIdx.x;
    const int blk  = blockIdx.x;
    const int gtid = blk * NTHR + t;

    // ---- phase 0: zero hist (65536 uints) + ctrl ----
    if (gtid < BB * NCODE) hist[gtid] = 0u;
    if (gtid < 2) ctrl[gtid] = 0ULL;
    grid.sync();

    // ---- phase 1: argmax -> atomic hist ----
    const int wave = gtid >> 6;         // 0..4095
    const int lane = t & 63;
    const int g = lane >> 4;            // 4 sixteen-lane groups per wave
    const int s = lane & 15;

    #pragma unroll
    for (int it = 0; it < 4; ++it) {
        const int p = wave * 16 + it * 4 + g;   // point for this lane-group
        // lane s holds elements [4s, 4s+4) of this point's 64 logits (16B load)
        const float4 u4 = *(const float4*)(u_logits + (size_t)p * 64 + s * 4);
        const float4 v4 = *(const float4*)(v_logits + (size_t)p * 64 + s * 4);
        const int mp = (s == 0) ? mask[p] : 0;  // issue early, hide under shuffles

        float um = u4.x; int ui = s * 4;
        if (u4.y > um) { um = u4.y; ui = s * 4 + 1; }
        if (u4.z > um) { um = u4.z; ui = s * 4 + 2; }
        if (u4.w > um) { um = u4.w; ui = s * 4 + 3; }
        float vm = v4.x; int vi = s * 4;
        if (v4.y > vm) { vm = v4.y; vi = s * 4 + 1; }
        if (v4.z > vm) { vm = v4.z; vi = s * 4 + 2; }
        if (v4.w > vm) { vm = v4.w; vi = s * 4 + 3; }

        // butterfly within each 16-lane group; first-index tie-break
        #pragma unroll
        for (int off = 8; off > 0; off >>= 1) {
            float oum = __shfl_xor(um, off, 64);
            int   oui = __shfl_xor(ui, off, 64);
            if (oum > um || (oum == um && oui < ui)) { um = oum; ui = oui; }
            float ovm = __shfl_xor(vm, off, 64);
            int   ovi = __shfl_xor(vi, off, 64);
            if (ovm > vm || (ovm == vm && ovi < vi)) { vm = ovm; vi = ovi; }
        }

        if (s == 0 && mp != 0 && ui > 0 && vi > 0) {
            const int b = p >> 12;      // p / N
            atomicAdd(&hist[(b << 12) | (ui << 6) | vi], 1u);
        }
    }
    grid.sync();

    // ---- phase 2: per-batch scan + combine ----
    if (blk < BB) {
        __shared__ long long wave_sums[16];
        const unsigned int* hb = hist + (blk << 12);
        long long acc = 0;
        #pragma unroll
        for (int i = t; i < NCODE; i += NTHR) {
            const long long c = (long long)hb[i];
            acc += c * (c - 1);         // ordered duplicate pairs
        }
        #pragma unroll
        for (int off = 32; off > 0; off >>= 1)
            acc += __shfl_xor(acc, off, 64);
        if ((t & 63) == 0) wave_sums[t >> 6] = acc;
        __syncthreads();
        if (t == 0) {
            long long part = 0;
            #pragma unroll
            for (int w = 0; w < 16; ++w) part += wave_sums[w];
            atomicAdd(&ctrl[0], (unsigned long long)part);
            __threadfence();
            const unsigned long long old = atomicAdd(&ctrl[1], 1ULL);
            if (old == (unsigned long long)(BB - 1)) {
                const unsigned long long total = atomicAdd(&ctrl[0], 0ULL);
                out[0] = (float)total * (WEIGHT / (2.0f * (float)BB));
            }
        }
    }
}

extern "C" void kernel_launch(void* const* d_in, const int* in_sizes, int n_in,
                              void* d_out, int out_size, void* d_ws, size_t ws_size,
                              hipStream_t stream) {
    const float* u_logits = (const float*)d_in[0];
    const float* v_logits = (const float*)d_in[1];
    const int*   mask     = (const int*)d_in[2];
    float* out = (float*)d_out;

    unsigned int* hist = (unsigned int*)d_ws;                                  // 256 KB
    unsigned long long* ctrl =
        (unsigned long long*)((char*)d_ws + (size_t)BB * NCODE * sizeof(unsigned int));

    void* args[] = { (void*)&u_logits, (void*)&v_logits, (void*)&mask,
                     (void*)&hist, (void*)&ctrl, (void*)&out };
    hipLaunchCooperativeKernel((const void*)uniq_fused_kernel,
                               dim3(NBLK), dim3(NTHR), args, 0, stream);
}

// Round 6
// 15.508 us; speedup vs baseline: 4.6259x; 4.6259x over previous
//
#include <hip/hip_runtime.h>

// Problem constants (from reference setup_inputs): B=16, N=4096, n_u=n_v=64.
#define BB 16
#define NN 4096
#define NPTS (BB * NN)      // 65536 points
#define NCODE 4096          // 64*64 codes per batch
#define WEIGHT 0.1f
#define INVALID_CODE 0xFFFFu

#define K1_BLOCKS 256
#define K1_THREADS 1024     // 16 waves/block, 4 pts/wave/iter, 4 iters -> 256 pts/block

// K1: 16-lane-group float4 argmax (proven absmax-0 in R4). Each group owns one
// point per iter: lane s holds elements [4s,4s+4) of the 64 logits (16B load),
// 3 scalar compares + 4-step butterfly, first-index tie-break (jnp.argmax).
// Leader writes u16 code (u*64+v) or INVALID. Also zeroes K2's ctrl block.
__global__ __launch_bounds__(K1_THREADS) void uniq_code_kernel(
    const float* __restrict__ u_logits,
    const float* __restrict__ v_logits,
    const int* __restrict__ mask,
    unsigned short* __restrict__ codes,
    unsigned long long* __restrict__ ctrl)
{
    const int t   = threadIdx.x;
    const int blk = blockIdx.x;
    const int g   = t >> 4;            // 64 sixteen-lane groups per block
    const int s   = t & 15;

    if (blk == 0 && t < 2) ctrl[t] = 0ULL;   // acc, done-counter for K2

    #pragma unroll
    for (int it = 0; it < 4; ++it) {
        const int p = blk * 256 + it * 64 + g;
        const float4 u4 = *(const float4*)(u_logits + (size_t)p * 64 + s * 4);
        const float4 v4 = *(const float4*)(v_logits + (size_t)p * 64 + s * 4);
        const int mp = (s == 0) ? mask[p] : 0;

        float um = u4.x; int ui = s * 4;
        if (u4.y > um) { um = u4.y; ui = s * 4 + 1; }
        if (u4.z > um) { um = u4.z; ui = s * 4 + 2; }
        if (u4.w > um) { um = u4.w; ui = s * 4 + 3; }
        float vm = v4.x; int vi = s * 4;
        if (v4.y > vm) { vm = v4.y; vi = s * 4 + 1; }
        if (v4.z > vm) { vm = v4.z; vi = s * 4 + 2; }
        if (v4.w > vm) { vm = v4.w; vi = s * 4 + 3; }

        #pragma unroll
        for (int off = 8; off > 0; off >>= 1) {   // 16-lane butterfly
            float oum = __shfl_xor(um, off, 64);
            int   oui = __shfl_xor(ui, off, 64);
            if (oum > um || (oum == um && oui < ui)) { um = oum; ui = oui; }
            float ovm = __shfl_xor(vm, off, 64);
            int   ovi = __shfl_xor(vi, off, 64);
            if (ovm > vm || (ovm == vm && ovi < vi)) { vm = ovm; vi = ovi; }
        }

        if (s == 0) {
            unsigned short code = (unsigned short)INVALID_CODE;
            if (mp != 0 && ui > 0 && vi > 0)
                code = (unsigned short)((ui << 6) | vi);
            codes[p] = code;                      // unconditional: no stale state
        }
    }
}

// K2: one block per batch. LDS histogram over the batch's 4096 codes,
// Sum c*(c-1) local, then fenced done-counter combine (proven R3);
// the 16th block writes the scalar.
__global__ __launch_bounds__(1024) void uniq_batch_kernel(
    const unsigned short* __restrict__ codes,
    unsigned long long* __restrict__ ctrl,
    float* __restrict__ out)
{
    __shared__ unsigned int h[NCODE];       // 16 KB
    __shared__ long long wave_sums[16];

    const int t = threadIdx.x;
    const int b = blockIdx.x;

    #pragma unroll
    for (int i = t; i < NCODE; i += 1024) h[i] = 0u;
    __syncthreads();

    // This batch's 4096 codes = 1024 uint2 words; one 8B load per thread.
    const uint2 w2 = ((const uint2*)(codes + (size_t)b * NN))[t];
    #pragma unroll
    for (int k = 0; k < 2; ++k) {
        const unsigned int w = (k == 0) ? w2.x : w2.y;
        const unsigned int c0 = w & 0xFFFFu;
        const unsigned int c1 = w >> 16;
        if (c0 != INVALID_CODE) atomicAdd(&h[c0], 1u);
        if (c1 != INVALID_CODE) atomicAdd(&h[c1], 1u);
    }
    __syncthreads();

    long long acc = 0;
    #pragma unroll
    for (int i = t; i < NCODE; i += 1024) {
        const long long c = (long long)h[i];
        acc += c * (c - 1);                 // ordered duplicate pairs
    }

    #pragma unroll
    for (int off = 32; off > 0; off >>= 1)
        acc += __shfl_xor(acc, off, 64);

    if ((t & 63) == 0) wave_sums[t >> 6] = acc;
    __syncthreads();

    if (t == 0) {
        long long partial = 0;
        #pragma unroll
        for (int w = 0; w < 16; ++w) partial += wave_sums[w];
        atomicAdd(&ctrl[0], (unsigned long long)partial);
        __threadfence();
        const unsigned long long old = atomicAdd(&ctrl[1], 1ULL);
        if (old == (unsigned long long)(BB - 1)) {
            const unsigned long long total = atomicAdd(&ctrl[0], 0ULL);
            out[0] = (float)total * (WEIGHT / (2.0f * (float)BB));
        }
    }
}

extern "C" void kernel_launch(void* const* d_in, const int* in_sizes, int n_in,
                              void* d_out, int out_size, void* d_ws, size_t ws_size,
                              hipStream_t stream) {
    const float* u_logits = (const float*)d_in[0];
    const float* v_logits = (const float*)d_in[1];
    const int*   mask     = (const int*)d_in[2];
    float* out = (float*)d_out;

    unsigned short*     codes = (unsigned short*)d_ws;                     // 128 KB
    unsigned long long* ctrl  = (unsigned long long*)((char*)d_ws + 131072);

    uniq_code_kernel<<<K1_BLOCKS, K1_THREADS, 0, stream>>>(
        u_logits, v_logits, mask, codes, ctrl);
    uniq_batch_kernel<<<BB, 1024, 0, stream>>>(codes, ctrl, out);
}

// Round 7
// 14.696 us; speedup vs baseline: 4.8814x; 1.0552x over previous
//
#include <hip/hip_runtime.h>

// Problem constants (from reference setup_inputs): B=16, N=4096, n_u=n_v=64.
#define BB 16
#define NN 4096
#define NPTS (BB * NN)      // 65536 points
#define NCODE 4096          // 64*64 codes per batch
#define WEIGHT 0.1f
#define INVALID_CODE 0xFFFFu

#define K1_BLOCKS 1024
#define K1_THREADS 1024     // 16 waves/block, 4 pts/wave, 1 iter -> 64 pts/block

// K1: 16-lane-group float4 argmax (proven absmax-0 since R4). Each group owns
// one point: lane s holds elements [4s,4s+4) of the 64 logits (16B load),
// 3 scalar compares + 4-step butterfly, first-index tie-break (jnp.argmax).
// One point per wave-group (no loop): 16384 waves -> 16/SIMD for deep
// memory pipelining (K1 is BW-bound; VALU is ~15% of its time).
// Leader writes u16 code (u*64+v) or INVALID. Block 0 zeroes K2's ctrl.
__global__ __launch_bounds__(K1_THREADS) void uniq_code_kernel(
    const float* __restrict__ u_logits,
    const float* __restrict__ v_logits,
    const int* __restrict__ mask,
    unsigned short* __restrict__ codes,
    unsigned long long* __restrict__ ctrl)
{
    const int t   = threadIdx.x;
    const int blk = blockIdx.x;
    const int g   = t >> 4;            // 64 sixteen-lane groups per block
    const int s   = t & 15;

    if (blk == 0 && t < 2) ctrl[t] = 0ULL;   // acc, done-counter for K2

    const int p = blk * 64 + g;        // one point per group
    const float4 u4 = *(const float4*)(u_logits + (size_t)p * 64 + s * 4);
    const float4 v4 = *(const float4*)(v_logits + (size_t)p * 64 + s * 4);
    const int mp = (s == 0) ? mask[p] : 0;

    float um = u4.x; int ui = s * 4;
    if (u4.y > um) { um = u4.y; ui = s * 4 + 1; }
    if (u4.z > um) { um = u4.z; ui = s * 4 + 2; }
    if (u4.w > um) { um = u4.w; ui = s * 4 + 3; }
    float vm = v4.x; int vi = s * 4;
    if (v4.y > vm) { vm = v4.y; vi = s * 4 + 1; }
    if (v4.z > vm) { vm = v4.z; vi = s * 4 + 2; }
    if (v4.w > vm) { vm = v4.w; vi = s * 4 + 3; }

    #pragma unroll
    for (int off = 8; off > 0; off >>= 1) {   // 16-lane butterfly
        float oum = __shfl_xor(um, off, 64);
        int   oui = __shfl_xor(ui, off, 64);
        if (oum > um || (oum == um && oui < ui)) { um = oum; ui = oui; }
        float ovm = __shfl_xor(vm, off, 64);
        int   ovi = __shfl_xor(vi, off, 64);
        if (ovm > vm || (ovm == vm && ovi < vi)) { vm = ovm; vi = ovi; }
    }

    if (s == 0) {
        unsigned short code = (unsigned short)INVALID_CODE;
        if (mp != 0 && ui > 0 && vi > 0)
            code = (unsigned short)((ui << 6) | vi);
        codes[p] = code;                      // unconditional: no stale state
    }
}

// K2: one block per batch. Codes load hoisted above the LDS zero so its
// ~500cy global latency hides under the zero+barrier. LDS histogram,
// Sum c*(c-1), fenced done-counter combine (proven R3); 16th block writes out.
__global__ __launch_bounds__(1024) void uniq_batch_kernel(
    const unsigned short* __restrict__ codes,
    unsigned long long* __restrict__ ctrl,
    float* __restrict__ out)
{
    __shared__ unsigned int h[NCODE];       // 16 KB
    __shared__ long long wave_sums[16];

    const int t = threadIdx.x;
    const int b = blockIdx.x;

    // Issue the global load FIRST; consume after the LDS zero pass.
    const uint2 w2 = ((const uint2*)(codes + (size_t)b * NN))[t];

    #pragma unroll
    for (int i = t; i < NCODE; i += 1024) h[i] = 0u;
    __syncthreads();

    #pragma unroll
    for (int k = 0; k < 2; ++k) {
        const unsigned int w = (k == 0) ? w2.x : w2.y;
        const unsigned int c0 = w & 0xFFFFu;
        const unsigned int c1 = w >> 16;
        if (c0 != INVALID_CODE) atomicAdd(&h[c0], 1u);
        if (c1 != INVALID_CODE) atomicAdd(&h[c1], 1u);
    }
    __syncthreads();

    long long acc = 0;
    #pragma unroll
    for (int i = t; i < NCODE; i += 1024) {
        const long long c = (long long)h[i];
        acc += c * (c - 1);                 // ordered duplicate pairs
    }

    #pragma unroll
    for (int off = 32; off > 0; off >>= 1)
        acc += __shfl_xor(acc, off, 64);

    if ((t & 63) == 0) wave_sums[t >> 6] = acc;
    __syncthreads();

    if (t == 0) {
        long long partial = 0;
        #pragma unroll
        for (int w = 0; w < 16; ++w) partial += wave_sums[w];
        atomicAdd(&ctrl[0], (unsigned long long)partial);
        __threadfence();
        const unsigned long long old = atomicAdd(&ctrl[1], 1ULL);
        if (old == (unsigned long long)(BB - 1)) {
            const unsigned long long total = atomicAdd(&ctrl[0], 0ULL);
            out[0] = (float)total * (WEIGHT / (2.0f * (float)BB));
        }
    }
}

extern "C" void kernel_launch(void* const* d_in, const int* in_sizes, int n_in,
                              void* d_out, int out_size, void* d_ws, size_t ws_size,
                              hipStream_t stream) {
    const float* u_logits = (const float*)d_in[0];
    const float* v_logits = (const float*)d_in[1];
    const int*   mask     = (const int*)d_in[2];
    float* out = (float*)d_out;

    unsigned short*     codes = (unsigned short*)d_ws;                     // 128 KB
    unsigned long long* ctrl  = (unsigned long long*)((char*)d_ws + 131072);

    uniq_code_kernel<<<K1_BLOCKS, K1_THREADS, 0, stream>>>(
        u_logits, v_logits, mask, codes, ctrl);
    uniq_batch_kernel<<<BB, 1024, 0, stream>>>(codes, ctrl, out);
}